// Round 5
// baseline (134.345 us; speedup 1.0000x reference)
//
#include <hip/hip_runtime.h>

// Problem constants
#define DD 20          // hypervol spatial extent per axis
#define MM 32          // channel count m
#define OO 19          // output extent per axis (DD - RANK + 1, RANK=2)
#define NWIN (OO*OO*OO)                  // 6859 windows
#define WPB 4                            // windows per block (one per wave)
#define NBLK ((NWIN + WPB - 1) / WPB)    // 1715 blocks

// workspace layout (floats):
//   C[19][32][32]   NATURAL layout cosine table: C[k][i][j] = cos(2*pi*k/(i*32+j+2))
//   X[6859][608]    stage-1 output x rows (x[win][d][i])
#define CT_FLOATS (OO*MM*MM)         // 19456
#define XOFF CT_FLOATS
#define XROW (OO*MM)                 // 608 floats per window

__global__ __launch_bounds__(256) void build_tables_kernel(float* __restrict__ ws) {
    int idx = blockIdx.x * 256 + threadIdx.x;
    if (idx < CT_FLOATS) {
        int k = idx >> 10;        // axis position 0..18
        int r = idx & 1023;
        int i = r >> 5;
        int j = r & 31;
        float period = (float)(i * MM + j + 2);
        ws[idx] = cosf(6.28318530717958647692f * (float)k / period);
    }
}

// Wave-internal sync: LDS-counter drain only (no vmcnt drain) + compiler fence.
__device__ __forceinline__ void lds_sync() {
    __builtin_amdgcn_s_waitcnt(0xC07F);   // lgkmcnt(0); vmcnt/expcnt untouched
    __builtin_amdgcn_wave_barrier();
}

// Shared index helpers: one WAVE per (a,b,c) window, XCD-contiguous swizzle
// (1715 = 3*215 + 5*214, bijective).
__device__ __forceinline__ int swizzled_win(int raw, int w) {
    const int xcd = raw & 7;
    const int k   = raw >> 3;
    const int sb  = (xcd < 3) ? (xcd * 215 + k) : (645 + (xcd - 3) * 214 + k);
    return sb * WPB + w;
}

// ---- Stage 1: window pre-sum + Linear(M).  Low VGPR -> 8 waves/SIMD. ----
__global__ __launch_bounds__(256, 8) void stage1_kernel(
        const float* __restrict__ H, const float* __restrict__ Mw,
        float* __restrict__ ws) {
    __shared__ __align__(16) float sS[WPB][DD * MM];   // 8-shift pre-sums
    __shared__ __align__(16) float sW[WPB][OO * MM];   // window rows /16

    const int tid  = threadIdx.x;
    const int w    = tid >> 6;
    const int lane = tid & 63;
    const int i    = lane & 31;
    const int h    = lane >> 5;
    const int jb   = h * 16;

    const int win = swizzled_win(blockIdx.x, w);
    if (win >= NWIN) return;             // wave-uniform; no block barriers exist
    const int c = win % OO;
    const int b = (win / OO) % OO;
    const int a = win / (OO * OO);

    float* __restrict__ S = sS[w];
    float* __restrict__ W = sW[w];

    // phase 1: 8-shift (a,b,c) pre-sum over 640 floats; float4, 2.5 per lane
    {
        float4 a0 = make_float4(0.f,0.f,0.f,0.f);
        float4 a1 = a0, a2 = a0;
        #pragma unroll
        for (int da = 0; da < 2; ++da)
            #pragma unroll
            for (int db = 0; db < 2; ++db)
                #pragma unroll
                for (int dc = 0; dc < 2; ++dc) {
                    const float4* __restrict__ p = (const float4*)(
                        H + (size_t)((((a + da) * DD + (b + db)) * DD + (c + dc)) * DD) * MM);
                    float4 v0 = p[lane];
                    float4 v1 = p[64 + lane];
                    a0.x += v0.x; a0.y += v0.y; a0.z += v0.z; a0.w += v0.w;
                    a1.x += v1.x; a1.y += v1.y; a1.z += v1.z; a1.w += v1.w;
                    if (lane < 32) {
                        float4 v2 = p[128 + lane];
                        a2.x += v2.x; a2.y += v2.y; a2.z += v2.z; a2.w += v2.w;
                    }
                }
        ((float4*)S)[lane]      = a0;
        ((float4*)S)[64 + lane] = a1;
        if (lane < 32) ((float4*)S)[128 + lane] = a2;
    }
    lds_sync();

    // phase 1.5: W[d][j] = (S[d][j] + S[d+1][j]) / 16
    #pragma unroll
    for (int t = 0; t < 10; ++t) {
        const int idx = t * 64 + lane;
        if (idx < OO * MM)
            W[idx] = (S[idx] + S[idx + MM]) * 0.0625f;
    }
    lds_sync();

    // phase 2: x[d][i] = sum_j W[d][j] * Mw[i][j]  (j-half per lane + shfl)
    {
        float mt[16];                    // Mw natural layout: contiguous per lane
        #pragma unroll
        for (int q = 0; q < 4; ++q) {
            const float4 v = ((const float4*)(Mw + i * MM + jb))[q];
            mt[q*4+0] = v.x; mt[q*4+1] = v.y; mt[q*4+2] = v.z; mt[q*4+3] = v.w;
        }
        float* __restrict__ Xg = ws + XOFF + (size_t)win * XROW;
        #pragma unroll
        for (int d = 0; d < OO; ++d) {
            const float4* __restrict__ wr = (const float4*)(W + d * MM + jb);
            float t = 0.f;
            #pragma unroll
            for (int q = 0; q < 4; ++q) {
                const float4 v = wr[q];
                t += v.x * mt[q*4+0] + v.y * mt[q*4+1]
                   + v.z * mt[q*4+2] + v.w * mt[q*4+3];
            }
            t += __shfl_xor(t, 32, 64);
            if (h == 0) Xg[d * MM + i] = t;
        }
    }
}

// ---- Stage 2: cosine-modulated contraction via Chebyshev recurrence. ----
// No LDS at all; x rows read as broadcast dwordx4 from L2-resident ws.
__global__ __launch_bounds__(256, 6) void stage2_kernel(
        const float* __restrict__ ws, const float* __restrict__ P,
        float* __restrict__ out) {
    const int tid  = threadIdx.x;
    const int w    = tid >> 6;
    const int lane = tid & 63;
    const int i    = lane & 31;
    const int h    = lane >> 5;
    const int jb   = h * 16;

    const int win = swizzled_win(blockIdx.x, w);
    if (win >= NWIN) return;
    const int c = win % OO;
    const int b = (win / OO) % OO;
    const int a = win / (OO * OO);

    const float* __restrict__ C = ws;

    // init: qp = P .* C[a] .* C[b] .* C[c];  s1 = qp (d=0), s0 = qp*cos(w) (d=-1)
    float s0[16], s1[16], t2c[16];
    {
        const int ro = i * MM + jb;      // this lane's 16 contiguous j's
        #pragma unroll
        for (int q = 0; q < 4; ++q) {
            const float4 pv = ((const float4*)(P + ro))[q];
            const float4 va = ((const float4*)(C + a * (MM*MM) + ro))[q];
            const float4 vb = ((const float4*)(C + b * (MM*MM) + ro))[q];
            const float4 vc = ((const float4*)(C + c * (MM*MM) + ro))[q];
            const float4 c1 = ((const float4*)(C + 1 * (MM*MM) + ro))[q];
            const float qpx = pv.x * va.x * vb.x * vc.x;
            const float qpy = pv.y * va.y * vb.y * vc.y;
            const float qpz = pv.z * va.z * vb.z * vc.z;
            const float qpw = pv.w * va.w * vb.w * vc.w;
            s1[q*4+0] = qpx; s0[q*4+0] = qpx * c1.x; t2c[q*4+0] = c1.x + c1.x;
            s1[q*4+1] = qpy; s0[q*4+1] = qpy * c1.y; t2c[q*4+1] = c1.y + c1.y;
            s1[q*4+2] = qpz; s0[q*4+2] = qpz * c1.z; t2c[q*4+2] = c1.z + c1.z;
            s1[q*4+3] = qpw; s0[q*4+3] = qpw * c1.w; t2c[q*4+3] = c1.w + c1.w;
        }
    }

    const float* __restrict__ Xg = ws + XOFF + (size_t)win * XROW + jb;
    const size_t obase = (size_t)win * XROW;
    #pragma unroll
    for (int d = 0; d < OO; ++d) {
        float t = 0.f;
        #pragma unroll
        for (int q = 0; q < 4; ++q) {
            const float4 v = ((const float4*)(Xg + d * MM))[q];  // broadcast L2
            t += v.x * s1[q*4+0] + v.y * s1[q*4+1]
               + v.z * s1[q*4+2] + v.w * s1[q*4+3];
        }
        #pragma unroll
        for (int jj = 0; jj < 16; ++jj) {     // advance recurrence
            const float nx = __builtin_fmaf(t2c[jj], s1[jj], -s0[jj]);
            s0[jj] = s1[jj];
            s1[jj] = nx;
        }
        t += __shfl_xor(t, 32, 64);
        if (h == 0) out[obase + d * MM + i] = t;
    }
}

extern "C" void kernel_launch(void* const* d_in, const int* in_sizes, int n_in,
                              void* d_out, int out_size, void* d_ws, size_t ws_size,
                              hipStream_t stream) {
    const float* H  = (const float*)d_in[0];   // hypervol [20,20,20,20,32]
    const float* Mw = (const float*)d_in[1];   // M_w [32,32]
    const float* P  = (const float*)d_in[2];   // P   [32,32]
    float* out = (float*)d_out;
    float* ws  = (float*)d_ws;

    build_tables_kernel<<<CT_FLOATS / 256, 256, 0, stream>>>(ws);  // 76 blocks
    stage1_kernel<<<NBLK, 256, 0, stream>>>(H, Mw, ws);
    stage2_kernel<<<NBLK, 256, 0, stream>>>(ws, P, out);
}

// Round 6
// 106.940 us; speedup vs baseline: 1.2563x; 1.2563x over previous
//
#include <hip/hip_runtime.h>

// Problem constants
#define DD 20          // hypervol spatial extent per axis
#define MM 32          // channel count m
#define OO 19          // output extent per axis (DD - RANK + 1, RANK=2)
#define NWIN (OO*OO*OO)                  // 6859 windows
#define WPB 4                            // windows per block (one per wave)
#define NBLK ((NWIN + WPB - 1) / WPB)    // 1715 blocks

// workspace: C[19][32][32] natural layout, C[k][i][j] = cos(2*pi*k/(i*32+j+2))
#define CT_FLOATS (OO*MM*MM)             // 19456

// per-wave LDS slice: S (640 floats, aliased by X after phase 1.5) + W (608)
#define LSLICE 1248
#define WOFF 640

__global__ __launch_bounds__(256) void build_tables_kernel(float* __restrict__ ws) {
    int idx = blockIdx.x * 256 + threadIdx.x;
    if (idx < CT_FLOATS) {
        int k = idx >> 10;
        int r = idx & 1023;
        int i = r >> 5;
        int j = r & 31;
        float period = (float)(i * MM + j + 2);
        ws[idx] = cosf(6.28318530717958647692f * (float)k / period);
    }
}

// Wave-internal sync: LDS-counter drain only + compiler fence. No s_barrier,
// no vmcnt drain -> waves never convoy, global loads stay in flight.
__device__ __forceinline__ void lds_sync() {
    __builtin_amdgcn_s_waitcnt(0xC07F);   // lgkmcnt(0) only
    __builtin_amdgcn_wave_barrier();
}

// One WAVE per (a,b,c) window; 4 independent windows per block.
// Lane = (i = lane&31 channel, h = lane>>5 j-half). Phase 3: Chebyshev
// recurrence s_d = 2cosw*s_{d-1} - s_{d-2}, qp folded into the init.
__global__ __launch_bounds__(256, 5) void spatial_kernel(
        const float* __restrict__ H, const float* __restrict__ Mw,
        const float* __restrict__ P, const float* __restrict__ ws,
        float* __restrict__ out) {
    __shared__ __align__(16) float sLDS[WPB][LSLICE];

    const int tid  = threadIdx.x;
    const int w    = tid >> 6;
    const int lane = tid & 63;
    const int i    = lane & 31;
    const int h    = lane >> 5;
    const int jb   = h * 16;

    // XCD-contiguous block swizzle (1715 = 3*215 + 5*214, bijective)
    const int raw = blockIdx.x;
    const int xcd = raw & 7;
    const int k   = raw >> 3;
    const int sb  = (xcd < 3) ? (xcd * 215 + k) : (645 + (xcd - 3) * 214 + k);
    const int win = sb * WPB + w;
    if (win >= NWIN) return;             // wave-uniform; no block barriers exist
    const int c = win % OO;
    const int b = (win / OO) % OO;
    const int a = win / (OO * OO);

    const float* __restrict__ C = ws;
    float* __restrict__ S = sLDS[w];          // phase 1 pre-sums (640 floats)
    float* __restrict__ W = sLDS[w] + WOFF;   // window rows /16  (608 floats)
    float* __restrict__ X = sLDS[w];          // x rows -- aliases dead S

    // ---- phase 1: 8-shift (a,b,c) pre-sum, 640 floats, float4 ----
    {
        float4 a0 = make_float4(0.f, 0.f, 0.f, 0.f);
        float4 a1 = a0, a2 = a0;
        #pragma unroll
        for (int da = 0; da < 2; ++da)
            #pragma unroll
            for (int db = 0; db < 2; ++db)
                #pragma unroll
                for (int dc = 0; dc < 2; ++dc) {
                    const float4* __restrict__ p = (const float4*)(
                        H + (size_t)((((a + da) * DD + (b + db)) * DD + (c + dc)) * DD) * MM);
                    const float4 v0 = p[lane];
                    const float4 v1 = p[64 + lane];
                    a0.x += v0.x; a0.y += v0.y; a0.z += v0.z; a0.w += v0.w;
                    a1.x += v1.x; a1.y += v1.y; a1.z += v1.z; a1.w += v1.w;
                    if (lane < 32) {
                        const float4 v2 = p[128 + lane];
                        a2.x += v2.x; a2.y += v2.y; a2.z += v2.z; a2.w += v2.w;
                    }
                }
        ((float4*)S)[lane]      = a0;
        ((float4*)S)[64 + lane] = a1;
        if (lane < 32) ((float4*)S)[128 + lane] = a2;
    }
    lds_sync();

    // ---- phase 1.5: W[d][j] = (S[d][j] + S[d+1][j]) / 16 ----
    #pragma unroll
    for (int t = 0; t < 10; ++t) {
        const int idx = t * 64 + lane;
        if (idx < OO * MM)
            W[idx] = (S[idx] + S[idx + MM]) * 0.0625f;
    }
    lds_sync();

    // ---- phase 2: x[d][i] = sum_j W[d][j] * Mw[i][j] (j-half + shfl) ----
    {
        float mt[16];                    // natural layout: contiguous per lane
        #pragma unroll
        for (int q = 0; q < 4; ++q) {
            const float4 v = ((const float4*)(Mw + i * MM + jb))[q];
            mt[q*4+0] = v.x; mt[q*4+1] = v.y; mt[q*4+2] = v.z; mt[q*4+3] = v.w;
        }
        #pragma unroll
        for (int d = 0; d < OO; ++d) {
            const float4* __restrict__ wr = (const float4*)(W + d * MM + jb);
            float t = 0.f;
            #pragma unroll
            for (int q = 0; q < 4; ++q) {
                const float4 v = wr[q];
                t += v.x * mt[q*4+0] + v.y * mt[q*4+1]
                   + v.z * mt[q*4+2] + v.w * mt[q*4+3];
            }
            t += __shfl_xor(t, 32, 64);
            if (h == 0) X[d * MM + i] = t;   // X aliases dead S region
        }
    }
    lds_sync();

    // ---- phase 3: out[d][i] = sum_j x[d][j]*qp[i][j]*cos(w_ij*d) ----
    float s0[16], s1[16], t2c[16];
    {
        const int ro = i * MM + jb;          // lane's 16 contiguous j's
        #pragma unroll
        for (int q = 0; q < 4; ++q) {
            const float4 pv = ((const float4*)(P + ro))[q];
            const float4 va = ((const float4*)(C + a * (MM*MM) + ro))[q];
            const float4 vb = ((const float4*)(C + b * (MM*MM) + ro))[q];
            const float4 vc = ((const float4*)(C + c * (MM*MM) + ro))[q];
            const float4 c1 = ((const float4*)(C + 1 * (MM*MM) + ro))[q];
            const float qpx = pv.x * va.x * vb.x * vc.x;
            const float qpy = pv.y * va.y * vb.y * vc.y;
            const float qpz = pv.z * va.z * vb.z * vc.z;
            const float qpw = pv.w * va.w * vb.w * vc.w;
            s1[q*4+0] = qpx; s0[q*4+0] = qpx * c1.x; t2c[q*4+0] = c1.x + c1.x;
            s1[q*4+1] = qpy; s0[q*4+1] = qpy * c1.y; t2c[q*4+1] = c1.y + c1.y;
            s1[q*4+2] = qpz; s0[q*4+2] = qpz * c1.z; t2c[q*4+2] = c1.z + c1.z;
            s1[q*4+3] = qpw; s0[q*4+3] = qpw * c1.w; t2c[q*4+3] = c1.w + c1.w;
        }
    }
    const size_t obase = (size_t)win * (OO * MM);
    #pragma unroll
    for (int d = 0; d < OO; ++d) {
        const float4* __restrict__ xr = (const float4*)(X + d * MM + jb);
        float t = 0.f;
        #pragma unroll
        for (int q = 0; q < 4; ++q) {
            const float4 v = xr[q];
            t += v.x * s1[q*4+0] + v.y * s1[q*4+1]
               + v.z * s1[q*4+2] + v.w * s1[q*4+3];
        }
        #pragma unroll
        for (int jj = 0; jj < 16; ++jj) {     // advance recurrence
            const float nx = __builtin_fmaf(t2c[jj], s1[jj], -s0[jj]);
            s0[jj] = s1[jj];
            s1[jj] = nx;
        }
        t += __shfl_xor(t, 32, 64);
        if (h == 0) out[obase + d * MM + i] = t;
    }
}

extern "C" void kernel_launch(void* const* d_in, const int* in_sizes, int n_in,
                              void* d_out, int out_size, void* d_ws, size_t ws_size,
                              hipStream_t stream) {
    const float* H  = (const float*)d_in[0];   // hypervol [20,20,20,20,32]
    const float* Mw = (const float*)d_in[1];   // M_w [32,32]
    const float* P  = (const float*)d_in[2];   // P   [32,32]
    float* out = (float*)d_out;
    float* ws  = (float*)d_ws;

    build_tables_kernel<<<CT_FLOATS / 256, 256, 0, stream>>>(ws);  // 76 blocks
    spatial_kernel<<<NBLK, 256, 0, stream>>>(H, Mw, P, ws, out);
}

// Round 7
// 105.212 us; speedup vs baseline: 1.2769x; 1.0164x over previous
//
#include <hip/hip_runtime.h>

// Problem constants
#define DD 20          // hypervol spatial extent per axis
#define MM 32          // channel count m
#define OO 19          // output extent per axis (DD - RANK + 1, RANK=2)
#define NWIN (OO*OO*OO)                  // 6859 windows
#define WPB 4                            // windows per block (one per wave)
#define NBLK ((NWIN + WPB - 1) / WPB)    // 1715 blocks

// workspace: C[19][32][32] natural layout, C[k][i][j] = cos(2*pi*k/(i*32+j+2))
#define CT_FLOATS (OO*MM*MM)             // 19456

// per-wave LDS slice: S (640 floats, aliased by X after phase 1.5) + W (608)
#define LSLICE 1248
#define WOFF 640

__global__ __launch_bounds__(256) void build_tables_kernel(float* __restrict__ ws) {
    int idx = blockIdx.x * 256 + threadIdx.x;
    if (idx < CT_FLOATS) {
        int k = idx >> 10;
        int r = idx & 1023;
        int i = r >> 5;
        int j = r & 31;
        float period = (float)(i * MM + j + 2);
        ws[idx] = cosf(6.28318530717958647692f * (float)k / period);
    }
}

// Wave-internal sync: LDS-counter drain only + compiler fence. No s_barrier,
// no vmcnt drain -> waves never convoy, global loads stay in flight.
__device__ __forceinline__ void lds_sync() {
    __builtin_amdgcn_s_waitcnt(0xC07F);   // lgkmcnt(0) only
    __builtin_amdgcn_wave_barrier();
}

// One WAVE per (a,b,c) window; 4 independent windows per block.
// Lane = (i = lane&31 channel, h = lane>>5 j-half). Phase 3: Chebyshev
// recurrence s_d = 2cosw*s_{d-1} - s_{d-2}, qp folded into the init.
// launch_bounds min-waves MUST stay 4: phase 3 needs 48 persistent VGPRs;
// (256,5) capped VGPR at 102->44 and spilled the recurrence state (R6: 44.5us).
__global__ __launch_bounds__(256, 4) void spatial_kernel(
        const float* __restrict__ H, const float* __restrict__ Mw,
        const float* __restrict__ P, const float* __restrict__ ws,
        float* __restrict__ out) {
    __shared__ __align__(16) float sLDS[WPB][LSLICE];

    const int tid  = threadIdx.x;
    const int w    = tid >> 6;
    const int lane = tid & 63;
    const int i    = lane & 31;
    const int h    = lane >> 5;
    const int jb   = h * 16;

    // XCD-contiguous block swizzle (1715 = 3*215 + 5*214, bijective)
    const int raw = blockIdx.x;
    const int xcd = raw & 7;
    const int k   = raw >> 3;
    const int sb  = (xcd < 3) ? (xcd * 215 + k) : (645 + (xcd - 3) * 214 + k);
    const int win = sb * WPB + w;
    if (win >= NWIN) return;             // wave-uniform; no block barriers exist
    const int c = win % OO;
    const int b = (win / OO) % OO;
    const int a = win / (OO * OO);

    const float* __restrict__ C = ws;
    float* __restrict__ S = sLDS[w];          // phase 1 pre-sums (640 floats)
    float* __restrict__ W = sLDS[w] + WOFF;   // raw window sums  (608 floats)
    float* __restrict__ X = sLDS[w];          // x rows -- aliases dead S

    // hoist Mw row (pre-scaled by 1/16) so the loads fly alongside phase 1's
    // H loads (wave_barrier fences would otherwise pin them after two syncs)
    float mt[16];
    #pragma unroll
    for (int q = 0; q < 4; ++q) {
        const float4 v = ((const float4*)(Mw + i * MM + jb))[q];
        mt[q*4+0] = v.x * 0.0625f; mt[q*4+1] = v.y * 0.0625f;
        mt[q*4+2] = v.z * 0.0625f; mt[q*4+3] = v.w * 0.0625f;
    }

    // ---- phase 1: 8-shift (a,b,c) pre-sum, 640 floats, float4 ----
    {
        float4 a0 = make_float4(0.f, 0.f, 0.f, 0.f);
        float4 a1 = a0, a2 = a0;
        #pragma unroll
        for (int da = 0; da < 2; ++da)
            #pragma unroll
            for (int db = 0; db < 2; ++db)
                #pragma unroll
                for (int dc = 0; dc < 2; ++dc) {
                    const float4* __restrict__ p = (const float4*)(
                        H + (size_t)((((a + da) * DD + (b + db)) * DD + (c + dc)) * DD) * MM);
                    const float4 v0 = p[lane];
                    const float4 v1 = p[64 + lane];
                    a0.x += v0.x; a0.y += v0.y; a0.z += v0.z; a0.w += v0.w;
                    a1.x += v1.x; a1.y += v1.y; a1.z += v1.z; a1.w += v1.w;
                    if (lane < 32) {
                        const float4 v2 = p[128 + lane];
                        a2.x += v2.x; a2.y += v2.y; a2.z += v2.z; a2.w += v2.w;
                    }
                }
        ((float4*)S)[lane]      = a0;
        ((float4*)S)[64 + lane] = a1;
        if (lane < 32) ((float4*)S)[128 + lane] = a2;
    }
    lds_sync();

    // ---- phase 1.5: W[d][j] = S[d][j] + S[d+1][j]  (1/16 folded into mt) ----
    #pragma unroll
    for (int t = 0; t < 10; ++t) {
        const int idx = t * 64 + lane;
        if (idx < OO * MM)
            W[idx] = S[idx] + S[idx + MM];
    }
    lds_sync();

    // ---- phase 2: x[d][i] = sum_j W[d][j] * Mw[i][j]/16 (j-half + shfl) ----
    #pragma unroll
    for (int d = 0; d < OO; ++d) {
        const float4* __restrict__ wr = (const float4*)(W + d * MM + jb);
        float t = 0.f;
        #pragma unroll
        for (int q = 0; q < 4; ++q) {
            const float4 v = wr[q];
            t += v.x * mt[q*4+0] + v.y * mt[q*4+1]
               + v.z * mt[q*4+2] + v.w * mt[q*4+3];
        }
        t += __shfl_xor(t, 32, 64);
        if (h == 0) X[d * MM + i] = t;       // X aliases dead S region
    }
    lds_sync();

    // ---- phase 3: out[d][i] = sum_j x[d][j]*qp[i][j]*cos(w_ij*d) ----
    float s0[16], s1[16], t2c[16];
    {
        const int ro = i * MM + jb;          // lane's 16 contiguous j's
        #pragma unroll
        for (int q = 0; q < 4; ++q) {
            const float4 pv = ((const float4*)(P + ro))[q];
            const float4 va = ((const float4*)(C + a * (MM*MM) + ro))[q];
            const float4 vb = ((const float4*)(C + b * (MM*MM) + ro))[q];
            const float4 vc = ((const float4*)(C + c * (MM*MM) + ro))[q];
            const float4 c1 = ((const float4*)(C + 1 * (MM*MM) + ro))[q];
            const float qpx = pv.x * va.x * vb.x * vc.x;
            const float qpy = pv.y * va.y * vb.y * vc.y;
            const float qpz = pv.z * va.z * vb.z * vc.z;
            const float qpw = pv.w * va.w * vb.w * vc.w;
            s1[q*4+0] = qpx; s0[q*4+0] = qpx * c1.x; t2c[q*4+0] = c1.x + c1.x;
            s1[q*4+1] = qpy; s0[q*4+1] = qpy * c1.y; t2c[q*4+1] = c1.y + c1.y;
            s1[q*4+2] = qpz; s0[q*4+2] = qpz * c1.z; t2c[q*4+2] = c1.z + c1.z;
            s1[q*4+3] = qpw; s0[q*4+3] = qpw * c1.w; t2c[q*4+3] = c1.w + c1.w;
        }
    }
    const size_t obase = (size_t)win * (OO * MM);
    #pragma unroll
    for (int d = 0; d < OO; ++d) {
        const float4* __restrict__ xr = (const float4*)(X + d * MM + jb);
        float t = 0.f;
        #pragma unroll
        for (int q = 0; q < 4; ++q) {
            const float4 v = xr[q];
            t += v.x * s1[q*4+0] + v.y * s1[q*4+1]
               + v.z * s1[q*4+2] + v.w * s1[q*4+3];
        }
        #pragma unroll
        for (int jj = 0; jj < 16; ++jj) {     // advance recurrence
            const float nx = __builtin_fmaf(t2c[jj], s1[jj], -s0[jj]);
            s0[jj] = s1[jj];
            s1[jj] = nx;
        }
        t += __shfl_xor(t, 32, 64);
        if (h == 0) out[obase + d * MM + i] = t;
    }
}

extern "C" void kernel_launch(void* const* d_in, const int* in_sizes, int n_in,
                              void* d_out, int out_size, void* d_ws, size_t ws_size,
                              hipStream_t stream) {
    const float* H  = (const float*)d_in[0];   // hypervol [20,20,20,20,32]
    const float* Mw = (const float*)d_in[1];   // M_w [32,32]
    const float* P  = (const float*)d_in[2];   // P   [32,32]
    float* out = (float*)d_out;
    float* ws  = (float*)d_ws;

    build_tables_kernel<<<CT_FLOATS / 256, 256, 0, stream>>>(ws);  // 76 blocks
    spatial_kernel<<<NBLK, 256, 0, stream>>>(H, Mw, P, ws, out);
}

// Round 8
// 94.507 us; speedup vs baseline: 1.4215x; 1.1133x over previous
//
#include <hip/hip_runtime.h>

// Problem constants
#define DD 20          // hypervol spatial extent per axis
#define MM 32          // channel count m
#define OO 19          // output extent per axis (DD - RANK + 1, RANK=2)
#define NWIN (OO*OO*OO)                  // 6859 windows
#define WPB 4                            // windows per block (one per wave)
#define NBLK ((NWIN + WPB - 1) / WPB)    // 1715 blocks

// Lane mapping used by spatial_kernel: lane -> (i = lane&31, h = lane>>5),
// lane's j-range = [h*16, h*16+16). All tables are stored LANE-SWIZZLED so
// that a wave's float4 table read is one contiguous 1KB transaction:
//   CS[k][q][lane][e] = cos(2*pi*k / (i*32 + (h*16 + q*4 + e) + 2))
//   PS[q][lane][e]    = P [i][h*16 + q*4 + e]
//   MS[q][lane][e]    = Mw[i][h*16 + q*4 + e] / 16
#define CS_FLOATS (OO*MM*MM)             // 19456
#define PS_OFF CS_FLOATS                 // 19456
#define MS_OFF (PS_OFF + MM*MM)          // 20480
#define WS_FLOATS (MS_OFF + MM*MM)       // 21504

// per-wave LDS slice: S (640 floats, aliased by X after phase 1.5) + W (608)
#define LSLICE 1248
#define WOFF 640

__global__ __launch_bounds__(256) void build_tables_kernel(
        const float* __restrict__ Mw, const float* __restrict__ P,
        float* __restrict__ ws) {
    const int idx = blockIdx.x * 256 + threadIdx.x;
    if (idx < CS_FLOATS) {
        const int k    = idx >> 10;          // 0..18
        const int r    = idx & 1023;
        const int q    = r >> 8;             // 0..3
        const int lane = (r >> 2) & 63;
        const int e    = r & 3;
        const int i    = lane & 31;
        const int j    = (lane >> 5) * 16 + q * 4 + e;
        const float period = (float)(i * MM + j + 2);
        ws[idx] = cosf(6.28318530717958647692f * (float)k / period);
    } else if (idx < WS_FLOATS) {
        const int r    = (idx - PS_OFF) & 1023;
        const int q    = r >> 8;
        const int lane = (r >> 2) & 63;
        const int e    = r & 3;
        const int i    = lane & 31;
        const int j    = (lane >> 5) * 16 + q * 4 + e;
        ws[idx] = (idx < MS_OFF) ? P[i * MM + j]
                                 : Mw[i * MM + j] * 0.0625f;
    }
}

// Wave-internal sync: LDS-counter drain only + compiler fence. No s_barrier,
// no vmcnt drain -> waves never convoy, global loads stay in flight.
__device__ __forceinline__ void lds_sync() {
    __builtin_amdgcn_s_waitcnt(0xC07F);   // lgkmcnt(0) only
    __builtin_amdgcn_wave_barrier();
}

// One WAVE per (a,b,c) window; 4 independent windows per block.
// Phase 3: Chebyshev recurrence s_d = 2cosw*s_{d-1} - s_{d-2}, qp in init.
// launch_bounds min-waves MUST stay 4: phase 3 needs 48 persistent VGPRs;
// (256,5) capped VGPR at 102 and spilled the recurrence state (R6: 44.5us).
__global__ __launch_bounds__(256, 4) void spatial_kernel(
        const float* __restrict__ H, const float* __restrict__ ws,
        float* __restrict__ out) {
    __shared__ __align__(16) float sLDS[WPB][LSLICE];

    const int tid  = threadIdx.x;
    const int w    = tid >> 6;
    const int lane = tid & 63;
    const int i    = lane & 31;
    const int h    = lane >> 5;
    const int jb   = h * 16;

    // XCD-contiguous block swizzle (1715 = 3*215 + 5*214, bijective)
    const int raw = blockIdx.x;
    const int xcd = raw & 7;
    const int k   = raw >> 3;
    const int sb  = (xcd < 3) ? (xcd * 215 + k) : (645 + (xcd - 3) * 214 + k);
    const int win = sb * WPB + w;
    if (win >= NWIN) return;             // wave-uniform; no block barriers exist
    const int c = win % OO;
    const int b = (win / OO) % OO;
    const int a = win / (OO * OO);

    const float4* __restrict__ T = (const float4*)ws;   // all tables, float4 units
    float* __restrict__ S = sLDS[w];          // phase 1 pre-sums (640 floats)
    float* __restrict__ W = sLDS[w] + WOFF;   // raw window sums  (608 floats)
    float* __restrict__ X = sLDS[w];          // x rows -- aliases dead S

    // hoist Mw row (pre-scaled by 1/16): 4 coalesced dwordx4, in flight with H
    float mt[16];
    #pragma unroll
    for (int q = 0; q < 4; ++q) {
        const float4 v = T[(MS_OFF >> 2) + q * 64 + lane];
        mt[q*4+0] = v.x; mt[q*4+1] = v.y; mt[q*4+2] = v.z; mt[q*4+3] = v.w;
    }

    // ---- phase 1: 8-shift (a,b,c) pre-sum, 640 floats, float4 ----
    {
        float4 a0 = make_float4(0.f, 0.f, 0.f, 0.f);
        float4 a1 = a0, a2 = a0;
        #pragma unroll
        for (int da = 0; da < 2; ++da)
            #pragma unroll
            for (int db = 0; db < 2; ++db)
                #pragma unroll
                for (int dc = 0; dc < 2; ++dc) {
                    const float4* __restrict__ p = (const float4*)(
                        H + (size_t)((((a + da) * DD + (b + db)) * DD + (c + dc)) * DD) * MM);
                    const float4 v0 = p[lane];
                    const float4 v1 = p[64 + lane];
                    a0.x += v0.x; a0.y += v0.y; a0.z += v0.z; a0.w += v0.w;
                    a1.x += v1.x; a1.y += v1.y; a1.z += v1.z; a1.w += v1.w;
                    if (lane < 32) {
                        const float4 v2 = p[128 + lane];
                        a2.x += v2.x; a2.y += v2.y; a2.z += v2.z; a2.w += v2.w;
                    }
                }
        ((float4*)S)[lane]      = a0;
        ((float4*)S)[64 + lane] = a1;
        if (lane < 32) ((float4*)S)[128 + lane] = a2;
    }
    lds_sync();

    // ---- phase 1.5: W[d][j] = S[d][j] + S[d+1][j]  (1/16 folded into mt) ----
    #pragma unroll
    for (int t = 0; t < 10; ++t) {
        const int idx = t * 64 + lane;
        if (idx < OO * MM)
            W[idx] = S[idx] + S[idx + MM];
    }
    lds_sync();

    // ---- phase 2: x[d][i] = sum_j W[d][j] * Mw[i][j]/16 (j-half + shfl) ----
    #pragma unroll
    for (int d = 0; d < OO; ++d) {
        const float4* __restrict__ wr = (const float4*)(W + d * MM + jb);
        float t = 0.f;
        #pragma unroll
        for (int q = 0; q < 4; ++q) {
            const float4 v = wr[q];
            t += v.x * mt[q*4+0] + v.y * mt[q*4+1]
               + v.z * mt[q*4+2] + v.w * mt[q*4+3];
        }
        t += __shfl_xor(t, 32, 64);
        if (h == 0) X[d * MM + i] = t;       // X aliases dead S region
    }
    lds_sync();

    // ---- phase 3: out[d][i] = sum_j x[d][j]*qp[i][j]*cos(w_ij*d) ----
    // All table reads below are coalesced dwordx4 (lane-swizzled layout).
    float s0[16], s1[16], t2c[16];
    #pragma unroll
    for (int q = 0; q < 4; ++q) {
        const float4 pv = T[(PS_OFF >> 2) + q * 64 + lane];
        const float4 va = T[(a * 4 + q) * 64 + lane];
        const float4 vb = T[(b * 4 + q) * 64 + lane];
        const float4 vc = T[(c * 4 + q) * 64 + lane];
        const float4 c1 = T[(1 * 4 + q) * 64 + lane];
        const float qpx = pv.x * va.x * vb.x * vc.x;
        const float qpy = pv.y * va.y * vb.y * vc.y;
        const float qpz = pv.z * va.z * vb.z * vc.z;
        const float qpw = pv.w * va.w * vb.w * vc.w;
        s1[q*4+0] = qpx; s0[q*4+0] = qpx * c1.x; t2c[q*4+0] = c1.x + c1.x;
        s1[q*4+1] = qpy; s0[q*4+1] = qpy * c1.y; t2c[q*4+1] = c1.y + c1.y;
        s1[q*4+2] = qpz; s0[q*4+2] = qpz * c1.z; t2c[q*4+2] = c1.z + c1.z;
        s1[q*4+3] = qpw; s0[q*4+3] = qpw * c1.w; t2c[q*4+3] = c1.w + c1.w;
    }
    const size_t obase = (size_t)win * (OO * MM);
    #pragma unroll
    for (int d = 0; d < OO; ++d) {
        const float4* __restrict__ xr = (const float4*)(X + d * MM + jb);
        float t = 0.f;
        #pragma unroll
        for (int q = 0; q < 4; ++q) {
            const float4 v = xr[q];
            t += v.x * s1[q*4+0] + v.y * s1[q*4+1]
               + v.z * s1[q*4+2] + v.w * s1[q*4+3];
        }
        #pragma unroll
        for (int jj = 0; jj < 16; ++jj) {     // advance recurrence
            const float nx = __builtin_fmaf(t2c[jj], s1[jj], -s0[jj]);
            s0[jj] = s1[jj];
            s1[jj] = nx;
        }
        t += __shfl_xor(t, 32, 64);
        if (h == 0) out[obase + d * MM + i] = t;
    }
}

extern "C" void kernel_launch(void* const* d_in, const int* in_sizes, int n_in,
                              void* d_out, int out_size, void* d_ws, size_t ws_size,
                              hipStream_t stream) {
    const float* H  = (const float*)d_in[0];   // hypervol [20,20,20,20,32]
    const float* Mw = (const float*)d_in[1];   // M_w [32,32]
    const float* P  = (const float*)d_in[2];   // P   [32,32]
    float* out = (float*)d_out;
    float* ws  = (float*)d_ws;

    build_tables_kernel<<<WS_FLOATS / 256, 256, 0, stream>>>(Mw, P, ws);  // 84
    spatial_kernel<<<NBLK, 256, 0, stream>>>(H, ws, out);
}